// Round 3
// baseline (311.719 us; speedup 1.0000x reference)
//
#include <hip/hip_runtime.h>

typedef unsigned short u16;
typedef unsigned int u32;

typedef __attribute__((ext_vector_type(8))) short bf16x8;
typedef __attribute__((ext_vector_type(4))) float f32x4;

static __device__ __forceinline__ u16 f2bf(float f) {
    u32 u = __float_as_uint(f);
    u32 r = (u + 0x7FFFu + ((u >> 16) & 1u)) >> 16;
    return (u16)r;
}
static __device__ __forceinline__ float bf2f(u16 h) {
    return __uint_as_float(((u32)h) << 16);
}
static __device__ __forceinline__ u32 pack2(float a, float b) {
    return (u32)f2bf(a) | ((u32)f2bf(b) << 16);
}

// ---------------- fp32 -> bf16 convert (vectorized) ----------------
__global__ __launch_bounds__(256) void convert_bf16_kernel(const float* __restrict__ x,
                                                           u16* __restrict__ y, int n4) {
    int i = blockIdx.x * 256 + threadIdx.x;
    if (i < n4) {
        float4 v = ((const float4*)x)[i];
        ushort4 o;
        o.x = f2bf(v.x); o.y = f2bf(v.y); o.z = f2bf(v.z); o.w = f2bf(v.w);
        ((ushort4*)y)[i] = o;
    }
}

// ---- 3x W [K,N] fp32 -> W^T [N,K] bf16, one dispatch (z selects matrix) ----
__global__ __launch_bounds__(256) void transpose3_to_bf16_kernel(
    const float* __restrict__ W0, const float* __restrict__ W1, const float* __restrict__ W2,
    u16* __restrict__ T0, u16* __restrict__ T1, u16* __restrict__ T2, int D) {
    __shared__ float t[32][33];
    const float* W = (blockIdx.z == 0) ? W0 : (blockIdx.z == 1) ? W1 : W2;
    u16* WT = (blockIdx.z == 0) ? T0 : (blockIdx.z == 1) ? T1 : T2;
    int bx = blockIdx.x, by = blockIdx.y;
    int tx = threadIdx.x, ty = threadIdx.y;
#pragma unroll
    for (int i = ty; i < 32; i += 8)
        t[i][tx] = W[(long)(by * 32 + i) * D + bx * 32 + tx];
    __syncthreads();
#pragma unroll
    for (int i = ty; i < 32; i += 8)
        WT[(long)(bx * 32 + i) * D + by * 32 + tx] = f2bf(t[tx][i]);
}

__global__ __launch_bounds__(256) void concat_bias_kernel(const float* __restrict__ a,
                                                          const float* __restrict__ b,
                                                          float* __restrict__ o, int n) {
    int i = blockIdx.x * 256 + threadIdx.x;
    if (i < 2 * n) o[i] = (i < n) ? a[i] : b[i - n];
}

// ================= 128x128-tile GEMM, BK=32, dbuf 32 KB, 4 blocks/CU =================
// R3: ALL large GEMMs now run through this kernel with >=1024-block grids so 4 blocks
// (16 waves) co-reside per CU. Theory: R0-R2 showed every structure at 8 waves/CU
// sticks at ~580 TF / 22% MfmaUtil; the m97-ladder reference hits 874-912 TF with the
// SAME 2-barrier loop but 3-4 co-resident blocks/CU (cross-block TLP hides the
// barrier/vmcnt drain; m114). Resources: LDS 32KB x4 = 128KiB, VGPR 60 + 64 AGPR = 124
// <= 128 -> 4 blocks/CU fit.
// rs_mode: 0 = plain; 1 = softmax-numerator fusion (exp after scale/bias/mask, fp32
// row-sums via 4-lane-reduced atomics; safe because |scores*scale + mask| is small);
// 2 = multiply output rows by 1/rowsum (softmax denominator).
__global__ __launch_bounds__(256, 4) void gemm_bt_kernel(
    const u16* __restrict__ A, int lda, long sA,
    const u16* __restrict__ B, int ldb, long sB,
    void* __restrict__ C, int ldc, long sC, int c_bf16,
    const float* __restrict__ bias, int bias_mode,
    const float* __restrict__ madd, int mask_ld,
    float* __restrict__ rowsum, int rs_mode, int rs_ld, int swapxy,
    float scale, int K) {
    __shared__ __align__(16) u16 SMEM[2][256 * 32];  // As 128*32 + Bs 128*32 per buf
    const int bz = blockIdx.z;
    const u16* Ab = A + (long)bz * sA;
    const u16* Bb = B + (long)bz * sB;
    const int bxi = swapxy ? blockIdx.y : blockIdx.x;
    const int byi = swapxy ? blockIdx.x : blockIdx.y;
    const int tm = byi * 128, tn = bxi * 128;
    const int tid = threadIdx.x, wave = tid >> 6, lane = tid & 63;
    const int wm = (wave >> 1) * 64, wn = (wave & 1) * 64;
    const int lr = lane >> 2, c = lane & 3;
    const int fm = lane & 15, fq = lane >> 4;

    f32x4 acc[4][4];
#pragma unroll
    for (int i = 0; i < 4; i++)
#pragma unroll
        for (int j = 0; j < 4; j++) acc[i][j] = (f32x4){0.f, 0.f, 0.f, 0.f};

    const int T = K >> 5;

    auto stage = [&](int t, int buf) {
        u16* As = &SMEM[buf][0];
        u16* Bs = &SMEM[buf][128 * 32];
#pragma unroll
        for (int r = 0; r < 2; r++) {
            const int rl = r * 64 + wave * 16;
            const int row = rl + lr;
            const int kc = (t << 5) + ((c ^ ((row ^ (row >> 2)) & 3)) << 3);
            const u16* ga = Ab + (long)(tm + row) * lda + kc;
            const u16* gb = Bb + (long)(tn + row) * ldb + kc;
            __builtin_amdgcn_global_load_lds((const __attribute__((address_space(1))) void*)ga,
                                             (__attribute__((address_space(3))) void*)&As[rl * 32],
                                             16, 0, 0);
            __builtin_amdgcn_global_load_lds((const __attribute__((address_space(1))) void*)gb,
                                             (__attribute__((address_space(3))) void*)&Bs[rl * 32],
                                             16, 0, 0);
        }
    };

    stage(0, 0);
    __syncthreads();
    for (int t = 0; t < T; t++) {
        const int cur = t & 1;
        if (t + 1 < T) stage(t + 1, cur ^ 1);
        const u16* As = &SMEM[cur][0];
        const u16* Bs = &SMEM[cur][128 * 32];
        bf16x8 af[4], bfr[4];
#pragma unroll
        for (int i = 0; i < 4; i++) {
            int row = wm + i * 16 + fm;
            af[i] = *(const bf16x8*)&As[row * 32 + ((fq ^ ((row ^ (row >> 2)) & 3)) << 3)];
        }
#pragma unroll
        for (int j = 0; j < 4; j++) {
            int row = wn + j * 16 + fm;
            bfr[j] = *(const bf16x8*)&Bs[row * 32 + ((fq ^ ((row ^ (row >> 2)) & 3)) << 3)];
        }
#pragma unroll
        for (int i = 0; i < 4; i++)
#pragma unroll
            for (int j = 0; j < 4; j++)
                acc[i][j] = __builtin_amdgcn_mfma_f32_16x16x32_bf16(af[i], bfr[j], acc[i][j], 0, 0, 0);
        if (t + 1 < T) __syncthreads();
    }
    __syncthreads();

    float* EP = (float*)&SMEM[0][0] + wave * 1088;
    const int row16 = lane >> 2, cb = (lane & 3) * 16;
    float4 bc[4];
    if (bias_mode == 1) {
#pragma unroll
        for (int q = 0; q < 4; q++) bc[q] = *(const float4*)&bias[tn + wn + cb + q * 4];
    }
#pragma unroll
    for (int i = 0; i < 4; i++) {
#pragma unroll
        for (int j = 0; j < 4; j++)
#pragma unroll
            for (int r = 0; r < 4; r++)
                EP[(fq * 4 + r) * 68 + j * 16 + fm] = acc[i][j][r];
        const long grow = tm + wm + i * 16 + row16;
        float rb = (bias_mode == 2) ? bias[grow] : 0.f;
        float4 t4[4];
#pragma unroll
        for (int q = 0; q < 4; q++) {
            float4 v = *(const float4*)&EP[row16 * 68 + cb + q * 4];
            v.x = v.x * scale + rb; v.y = v.y * scale + rb;
            v.z = v.z * scale + rb; v.w = v.w * scale + rb;
            if (bias_mode == 1) { v.x += bc[q].x; v.y += bc[q].y; v.z += bc[q].z; v.w += bc[q].w; }
            if (madd) {
                float4 m4 = *(const float4*)&madd[grow * mask_ld + tn + wn + cb + q * 4];
                v.x += m4.x; v.y += m4.y; v.z += m4.z; v.w += m4.w;
            }
            t4[q] = v;
        }
        if (rs_mode == 1) {
            float s = 0.f;
#pragma unroll
            for (int q = 0; q < 4; q++) {
                t4[q].x = __expf(t4[q].x); t4[q].y = __expf(t4[q].y);
                t4[q].z = __expf(t4[q].z); t4[q].w = __expf(t4[q].w);
                s += t4[q].x + t4[q].y + t4[q].z + t4[q].w;
            }
            s += __shfl_xor(s, 1);
            s += __shfl_xor(s, 2);
            if ((lane & 3) == 0) atomicAdd(&rowsum[(long)bz * rs_ld + grow], s);
        } else if (rs_mode == 2) {
            float inv = 1.f / rowsum[(long)bz * rs_ld + grow];
#pragma unroll
            for (int q = 0; q < 4; q++) {
                t4[q].x *= inv; t4[q].y *= inv; t4[q].z *= inv; t4[q].w *= inv;
            }
        }
        if (c_bf16) {
            u16* dst = (u16*)C + (long)bz * sC + grow * ldc + tn + wn + cb;
            uint4 o0 = {pack2(t4[0].x, t4[0].y), pack2(t4[0].z, t4[0].w),
                        pack2(t4[1].x, t4[1].y), pack2(t4[1].z, t4[1].w)};
            uint4 o1 = {pack2(t4[2].x, t4[2].y), pack2(t4[2].z, t4[2].w),
                        pack2(t4[3].x, t4[3].y), pack2(t4[3].z, t4[3].w)};
            *(uint4*)dst = o0;
            *(uint4*)(dst + 8) = o1;
        } else {
            float* dst = (float*)C + (long)bz * sC + grow * ldc + tn + wn + cb;
#pragma unroll
            for (int q = 0; q < 4; q++) *(float4*)(dst + q * 4) = t4[q];
        }
    }
}

extern "C" void kernel_launch(void* const* d_in, const int* in_sizes, int n_in,
                              void* d_out, int out_size, void* d_ws, size_t ws_size,
                              hipStream_t stream) {
    const float* x    = (const float*)d_in[0];
    const float* mask = (const float*)d_in[1];
    const float* Wq   = (const float*)d_in[2];
    const float* bq   = (const float*)d_in[3];
    const float* Wk   = (const float*)d_in[4];
    const float* bk   = (const float*)d_in[5];
    const float* Wv   = (const float*)d_in[6];
    const float* bv   = (const float*)d_in[7];
    float* out = (float*)d_out;

    const int B = 4, S = 2048, D = 1024;
    const long MS = (long)B * S;  // 8192

    size_t need = (size_t)MS * D * 2 + (size_t)(2 * D) * D * 2 + (size_t)D * D * 2
                + (size_t)(2 * D) * 4 + (size_t)MS * (2 * D) * 2 + (size_t)D * MS * 2
                + (size_t)B * S * S * 2 + (size_t)B * S * 4;
    if (ws_size < need) return;

    char* ws = (char*)d_ws;
    u16*  xb   = (u16*)ws;  ws += (long)MS * D * 2;
    u16*  wqkt = (u16*)ws;  ws += (long)(2 * D) * D * 2;
    u16*  wvt  = (u16*)ws;  ws += (long)D * D * 2;
    float* bqk = (float*)ws; ws += (long)(2 * D) * 4;
    u16*  QK   = (u16*)ws;  ws += (long)MS * (2 * D) * 2;
    u16*  VT   = (u16*)ws;  ws += (long)D * MS * 2;
    u16*  sc   = (u16*)ws;  ws += (long)B * S * S * 2;
    float* rsum = (float*)ws; ws += (long)B * S * 4;

    const float SCALE = 0.03125f;  // 1/sqrt(1024)

    hipMemsetAsync(rsum, 0, (size_t)B * S * 4, stream);

    convert_bf16_kernel<<<(int)((MS * D / 4 + 255) / 256), 256, 0, stream>>>(x, xb, (int)(MS * D / 4));
    transpose3_to_bf16_kernel<<<dim3(32, 32, 3), dim3(32, 8), 0, stream>>>(
        Wq, Wk, Wv, wqkt, wqkt + (long)D * D, wvt, D);
    concat_bias_kernel<<<8, 256, 0, stream>>>(bq, bk, bqk, D);

    // QK projection: [8192, 2048] = x @ [Wq|Wk]^T + [bq|bk].
    // 128^2 tiles -> grid (16, 64) = 1024 blocks = 4/CU co-resident.
    gemm_bt_kernel<<<dim3(2 * D / 128, (int)(MS / 128), 1), 256, 0, stream>>>(
        xb, D, 0, wqkt, D, 0, QK, 2 * D, 0, 1, bqk, 1, nullptr, 0,
        nullptr, 0, 0, 0, 1.0f, D);
    // V^T [1024, 8192] bf16: 128^2 tiles, grid (64, 8) = 512 blocks (2/CU; next-round target)
    gemm_bt_kernel<<<dim3((int)(MS / 128), D / 128, 1), 256, 0, stream>>>(
        wvt, D, 0, xb, D, 0, VT, (int)MS, 0, 1, bv, 2, nullptr, 0,
        nullptr, 0, 0, 0, 1.0f, D);

    // scores: exp((Q.K^T)*scale + mask) -> bf16, rowsum accumulated (softmax numerator).
    // 128^2 tiles -> grid (16, 16, 4) = 1024 blocks = 4/CU co-resident.
    gemm_bt_kernel<<<dim3(S / 128, S / 128, B), 256, 0, stream>>>(
        QK, 2 * D, (long)S * 2 * D, QK + D, 2 * D, (long)S * 2 * D, sc, S, (long)S * S, 1,
        nullptr, 0, mask, S, rsum, 1, S, 0, SCALE, D);

    // PV: out = (exp-scores @ VT^T) / rowsum  (softmax denominator fused in epilogue).
    // swapxy=1 + grid (q-tiles, d-tiles): XCD = q%8 -> sc footprint 4 MB/XCD (L2-resident).
    gemm_bt_kernel<<<dim3(S / 128, D / 128, B), 256, 0, stream>>>(
        sc, S, (long)S * S, VT, (int)MS, (long)S, out, D, (long)S * D, 0,
        nullptr, 0, nullptr, 0, rsum, 2, S, 1, 1.0f, S);
}

// Round 4
// 281.577 us; speedup vs baseline: 1.1070x; 1.1070x over previous
//
#include <hip/hip_runtime.h>

typedef unsigned short u16;
typedef unsigned int u32;

typedef __attribute__((ext_vector_type(8))) short bf16x8;
typedef __attribute__((ext_vector_type(4))) float f32x4;

static __device__ __forceinline__ u16 f2bf(float f) {
    u32 u = __float_as_uint(f);
    u32 r = (u + 0x7FFFu + ((u >> 16) & 1u)) >> 16;
    return (u16)r;
}
static __device__ __forceinline__ float bf2f(u16 h) {
    return __uint_as_float(((u32)h) << 16);
}
static __device__ __forceinline__ u32 pack2(float a, float b) {
    return (u32)f2bf(a) | ((u32)f2bf(b) << 16);
}

// ---------------- fp32 -> bf16 convert (vectorized) ----------------
__global__ __launch_bounds__(256) void convert_bf16_kernel(const float* __restrict__ x,
                                                           u16* __restrict__ y, int n4) {
    int i = blockIdx.x * 256 + threadIdx.x;
    if (i < n4) {
        float4 v = ((const float4*)x)[i];
        ushort4 o;
        o.x = f2bf(v.x); o.y = f2bf(v.y); o.z = f2bf(v.z); o.w = f2bf(v.w);
        ((ushort4*)y)[i] = o;
    }
}

// ---- 3x W [K,N] fp32 -> W^T [N,K] bf16, one dispatch (z selects matrix) ----
__global__ __launch_bounds__(256) void transpose3_to_bf16_kernel(
    const float* __restrict__ W0, const float* __restrict__ W1, const float* __restrict__ W2,
    u16* __restrict__ T0, u16* __restrict__ T1, u16* __restrict__ T2, int D) {
    __shared__ float t[32][33];
    const float* W = (blockIdx.z == 0) ? W0 : (blockIdx.z == 1) ? W1 : W2;
    u16* WT = (blockIdx.z == 0) ? T0 : (blockIdx.z == 1) ? T1 : T2;
    int bx = blockIdx.x, by = blockIdx.y;
    int tx = threadIdx.x, ty = threadIdx.y;
#pragma unroll
    for (int i = ty; i < 32; i += 8)
        t[i][tx] = W[(long)(by * 32 + i) * D + bx * 32 + tx];
    __syncthreads();
#pragma unroll
    for (int i = ty; i < 32; i += 8)
        WT[(long)(bx * 32 + i) * D + by * 32 + tx] = f2bf(t[tx][i]);
}

__global__ __launch_bounds__(256) void concat_bias_kernel(const float* __restrict__ a,
                                                          const float* __restrict__ b,
                                                          float* __restrict__ o, int n) {
    int i = blockIdx.x * 256 + threadIdx.x;
    if (i < 2 * n) o[i] = (i < n) ? a[i] : b[i - n];
}

// =====================================================================================
// 256x256-tile, BK=64, 8-wave (2Mx4N), software-pipelined counted-vmcnt GEMM.
// (R1 structure, best measured for QK-proj + scores.)
// R4: madd is now bf16 (u16*) -- the fp32 mask was 67 MB of the scores dispatch's
// 82 MB FETCH_SIZE; bf16 halves it.
// rs_mode: 0 plain; 1 softmax numerator (exp + atomic rowsum; safe without max-sub
// because |scores*scale + mask| is small); 2 divide by rowsum.
// =====================================================================================
__global__ __launch_bounds__(512, 2) void gemm256_kernel(
    const u16* __restrict__ A, int lda, long sA,
    const u16* __restrict__ B, int ldb, long sB,
    void* __restrict__ C, int ldc, long sC, int c_bf16,
    const float* __restrict__ bias, int bias_mode,
    const u16* __restrict__ madd, int mask_ld,
    float* __restrict__ rowsum, int rs_mode, int rs_ld,
    float scale, int K) {
    __shared__ __align__(16) u16 SMEM[2][2 * 256 * 64];  // per buf: A 16K elems | B 16K elems
    const int bz = blockIdx.z;
    const u16* Ab = A + (long)bz * sA;
    const u16* Bb = B + (long)bz * sB;
    // XCD-aware bijective swizzle over the (x,y) plane (nwg per z-plane % 8 == 0).
    int bx, by;
    {
        const int gx = gridDim.x;
        int flat = blockIdx.y * gx + blockIdx.x;
        const int cpx = (gx * gridDim.y) >> 3;
        flat = (flat & 7) * cpx + (flat >> 3);
        bx = flat % gx;
        by = flat / gx;
    }
    const int tm = by << 8, tn = bx << 8;
    const int tid = threadIdx.x, wave = tid >> 6, lane = tid & 63;
    const int wq = wave & 3;          // n-group 0..3
    const int wm = (wave >> 2) << 7;  // 0 or 128
    const int wn = wq << 6;           // 0,64,128,192
    const int fm = lane & 15, fq = lane >> 4;
    const int T = K >> 6;

    f32x4 acc[8][4];
#pragma unroll
    for (int i = 0; i < 8; i++)
#pragma unroll
        for (int j = 0; j < 4; j++) acc[i][j] = (f32x4){0.f, 0.f, 0.f, 0.f};

    const int srow = tid >> 3;   // 0..63: row within a 64-row gload issue
    const int sslot = tid & 7;   // 8B-pair slot 0..7

    auto stageA = [&](int t, int half) {  // half 0: LDS rows {0-63,128-191}; 1: hi
        u16* dst = &SMEM[t & 1][0];
        const int kb = t << 6;
#pragma unroll
        for (int blk = 0; blk < 2; blk++) {
            const int r0 = blk * 128 + half * 64;
            const int r = r0 + srow;
            const int gk = kb + ((sslot ^ (r & 7)) << 3);
            const u16* ga = Ab + (long)(tm + r) * lda + gk;
            __builtin_amdgcn_global_load_lds(
                (const __attribute__((address_space(1))) void*)ga,
                (__attribute__((address_space(3))) void*)&dst[(r0 + wave * 8) * 64], 16, 0, 0);
        }
    };
    auto stageB = [&](int t, int half) {  // half 0: LDS rows 0-127 (j-lo class); 1: 128-255
        u16* dst = &SMEM[t & 1][256 * 64];
        const int kb = t << 6;
#pragma unroll
        for (int blk = 0; blk < 2; blk++) {
            const int r0 = half * 128 + blk * 64;
            const int r = r0 + srow;  // LDS row (class-major remap)
            const int g = ((r >> 5) & 3) * 64 + (r >> 7) * 32 + (r & 31);  // global row in tile
            const int gk = kb + ((sslot ^ (r & 7)) << 3);
            const u16* gb = Bb + (long)(tn + g) * ldb + gk;
            __builtin_amdgcn_global_load_lds(
                (const __attribute__((address_space(1))) void*)gb,
                (__attribute__((address_space(3))) void*)&dst[(r0 + wave * 8) * 64], 16, 0, 0);
        }
    };

    auto read_a4 = [&](const u16* Ls, bf16x8 (&d)[4][2], int base) {
#pragma unroll
        for (int i = 0; i < 4; i++) {
            const int ra = base + i * 16 + fm;
            const int sw = ra & 7;
#pragma unroll
            for (int kh = 0; kh < 2; kh++)
                d[i][kh] = *(const bf16x8*)&Ls[ra * 64 + (((kh * 4 + fq) ^ sw) << 3)];
        }
    };
    auto read_b2 = [&](const u16* Ls, bf16x8 (&d)[2][2], int base) {
#pragma unroll
        for (int j = 0; j < 2; j++) {
            const int rb = base + j * 16 + fm;
            const int sw = rb & 7;
#pragma unroll
            for (int kh = 0; kh < 2; kh++)
                d[j][kh] = *(const bf16x8*)&Ls[rb * 64 + (((kh * 4 + fq) ^ sw) << 3)];
        }
    };

    // Prologue: tile0 fully + tile1 A-lo,B-lo,A-hi. vmcnt(6) => tile0 landed.
    stageA(0, 0); stageB(0, 0); stageA(0, 1); stageB(0, 1);
    if (T > 1) {
        stageA(1, 0); stageB(1, 0); stageA(1, 1);
        asm volatile("s_waitcnt vmcnt(6)" ::: "memory");
    } else {
        asm volatile("s_waitcnt vmcnt(0)" ::: "memory");
    }
    __builtin_amdgcn_sched_barrier(0);
    __builtin_amdgcn_s_barrier();
    __builtin_amdgcn_sched_barrier(0);

    bf16x8 alo[4][2], ahi[4][2], blo[2][2], bhi[2][2];
    read_a4(&SMEM[0][0], alo, wm);
    read_b2(&SMEM[0][256 * 64], blo, wq * 32);

    for (int u = 0; u < T; ++u) {
        const u16* As = &SMEM[u & 1][0];
        const u16* Bs = &SMEM[u & 1][256 * 64];
        const u16* As2 = &SMEM[(u + 1) & 1][0];
        const u16* Bs2 = &SMEM[(u + 1) & 1][256 * 64];
        // ---------- P1: stage B-hi(u+1); read bhi(u); Q1 = alo x blo ----------
        if (u + 1 < T) stageB(u + 1, 1);
        read_b2(Bs, bhi, 128 + wq * 32);
        __builtin_amdgcn_sched_barrier(0);
        __builtin_amdgcn_s_setprio(1);
#pragma unroll
        for (int kh = 0; kh < 2; kh++)
#pragma unroll
            for (int i = 0; i < 4; i++)
#pragma unroll
                for (int j = 0; j < 2; j++)
                    acc[i][j] = __builtin_amdgcn_mfma_f32_16x16x32_bf16(alo[i][kh], blo[j][kh], acc[i][j], 0, 0, 0);
        __builtin_amdgcn_s_setprio(0);
        __builtin_amdgcn_sched_barrier(0);
        __builtin_amdgcn_s_barrier();
        __builtin_amdgcn_sched_barrier(0);
        // ---------- P2: stage A-lo(u+2); read ahi(u); Q2 = alo x bhi ----------
        if (u + 2 < T) stageA(u + 2, 0);
        read_a4(As, ahi, wm + 64);
        __builtin_amdgcn_sched_barrier(0);
        __builtin_amdgcn_s_setprio(1);
#pragma unroll
        for (int kh = 0; kh < 2; kh++)
#pragma unroll
            for (int i = 0; i < 4; i++)
#pragma unroll
                for (int j = 0; j < 2; j++)
                    acc[i][2 + j] = __builtin_amdgcn_mfma_f32_16x16x32_bf16(alo[i][kh], bhi[j][kh], acc[i][2 + j], 0, 0, 0);
        __builtin_amdgcn_s_setprio(0);
        __builtin_amdgcn_sched_barrier(0);
        __builtin_amdgcn_s_barrier();
        __builtin_amdgcn_sched_barrier(0);
        // ---------- P3: stage B-lo(u+2); Q3 = ahi x blo ----------
        if (u + 2 < T) stageB(u + 2, 0);
        __builtin_amdgcn_sched_barrier(0);
        __builtin_amdgcn_s_setprio(1);
#pragma unroll
        for (int kh = 0; kh < 2; kh++)
#pragma unroll
            for (int i = 0; i < 4; i++)
#pragma unroll
                for (int j = 0; j < 2; j++)
                    acc[4 + i][j] = __builtin_amdgcn_mfma_f32_16x16x32_bf16(ahi[i][kh], blo[j][kh], acc[4 + i][j], 0, 0, 0);
        __builtin_amdgcn_s_setprio(0);
        __builtin_amdgcn_sched_barrier(0);
        __builtin_amdgcn_s_barrier();
        __builtin_amdgcn_sched_barrier(0);
        // ---------- P4: stage A-hi(u+2); vmcnt; barrier; read alo/blo(u+1); Q4 ----------
        if (u + 2 < T) {
            stageA(u + 2, 1);
            asm volatile("s_waitcnt vmcnt(6)" ::: "memory");
        } else {
            asm volatile("s_waitcnt vmcnt(0)" ::: "memory");
        }
        __builtin_amdgcn_sched_barrier(0);
        __builtin_amdgcn_s_barrier();
        __builtin_amdgcn_sched_barrier(0);
        if (u + 1 < T) {
            read_a4(As2, alo, wm);
            read_b2(Bs2, blo, wq * 32);
        }
        __builtin_amdgcn_sched_barrier(0);
        __builtin_amdgcn_s_setprio(1);
#pragma unroll
        for (int kh = 0; kh < 2; kh++)
#pragma unroll
            for (int i = 0; i < 4; i++)
#pragma unroll
                for (int j = 0; j < 2; j++)
                    acc[4 + i][2 + j] = __builtin_amdgcn_mfma_f32_16x16x32_bf16(ahi[i][kh], bhi[j][kh], acc[4 + i][2 + j], 0, 0, 0);
        __builtin_amdgcn_s_setprio(0);
    }
    __syncthreads();  // full drain before LDS reuse in epilogue

    // -------- epilogue: LDS transpose per 16-row i-block, fused bias/mask/exp/rowsum --------
    float* EP = (float*)&SMEM[0][0] + wave * 1088;
    const int row16 = lane >> 2, cb = (lane & 3) * 16;
    float4 bc[4];
    if (bias_mode == 1) {
#pragma unroll
        for (int q = 0; q < 4; q++) bc[q] = *(const float4*)&bias[tn + wn + cb + q * 4];
    }
#pragma unroll
    for (int i = 0; i < 8; i++) {
#pragma unroll
        for (int j = 0; j < 4; j++)
#pragma unroll
            for (int r = 0; r < 4; r++)
                EP[(fq * 4 + r) * 68 + j * 16 + fm] = acc[i][j][r];
        const long grow = tm + wm + i * 16 + row16;
        float rb = (bias_mode == 2) ? bias[grow] : 0.f;
        float4 t4[4];
#pragma unroll
        for (int q = 0; q < 4; q++) {
            float4 v = *(const float4*)&EP[row16 * 68 + cb + q * 4];
            v.x = v.x * scale + rb; v.y = v.y * scale + rb;
            v.z = v.z * scale + rb; v.w = v.w * scale + rb;
            if (bias_mode == 1) { v.x += bc[q].x; v.y += bc[q].y; v.z += bc[q].z; v.w += bc[q].w; }
            if (madd) {
                ushort4 m4 = *(const ushort4*)&madd[grow * mask_ld + tn + wn + cb + q * 4];
                v.x += bf2f(m4.x); v.y += bf2f(m4.y); v.z += bf2f(m4.z); v.w += bf2f(m4.w);
            }
            t4[q] = v;
        }
        if (rs_mode == 1) {
            float s = 0.f;
#pragma unroll
            for (int q = 0; q < 4; q++) {
                t4[q].x = __expf(t4[q].x); t4[q].y = __expf(t4[q].y);
                t4[q].z = __expf(t4[q].z); t4[q].w = __expf(t4[q].w);
                s += t4[q].x + t4[q].y + t4[q].z + t4[q].w;
            }
            s += __shfl_xor(s, 1);
            s += __shfl_xor(s, 2);
            if ((lane & 3) == 0) atomicAdd(&rowsum[(long)bz * rs_ld + grow], s);
        } else if (rs_mode == 2) {
            float inv = 1.f / rowsum[(long)bz * rs_ld + grow];
#pragma unroll
            for (int q = 0; q < 4; q++) {
                t4[q].x *= inv; t4[q].y *= inv; t4[q].z *= inv; t4[q].w *= inv;
            }
        }
        if (c_bf16) {
            u16* dst = (u16*)C + (long)bz * sC + grow * ldc + tn + wn + cb;
            uint4 o0 = {pack2(t4[0].x, t4[0].y), pack2(t4[0].z, t4[0].w),
                        pack2(t4[1].x, t4[1].y), pack2(t4[1].z, t4[1].w)};
            uint4 o1 = {pack2(t4[2].x, t4[2].y), pack2(t4[2].z, t4[2].w),
                        pack2(t4[3].x, t4[3].y), pack2(t4[3].z, t4[3].w)};
            *(uint4*)dst = o0;
            *(uint4*)(dst + 8) = o1;
        } else {
            float* dst = (float*)C + (long)bz * sC + grow * ldc + tn + wn + cb;
#pragma unroll
            for (int q = 0; q < 4; q++) *(float4*)(dst + q * 4) = t4[q];
        }
    }
}

// ================= 128x128-tile GEMM, BK=32, dbuf 32 KB (VT + PV) =================
// xcd_mode 0: direct (bxi,byi,bzi) = blockIdx.
// xcd_mode 1 (PV; requires grid (8,16,4)): XCD = blockIdx.x (gx=8 => linear%8 = x).
//   Each XCD owns one batch-half region (8q x 8d, single z): per-XCD co-resident
//   working set drops ~20 MB -> 8 MB (sc q-panels 4 MB + VT d-panels 4 MB).
//   z = xcd>>1; s = by + 16*bz in [0,64): q-tile = (xcd&1)*8 + s>>3, d-tile = s&7.
__global__ __launch_bounds__(256, 4) void gemm_bt_kernel(
    const u16* __restrict__ A, int lda, long sA,
    const u16* __restrict__ B, int ldb, long sB,
    void* __restrict__ C, int ldc, long sC, int c_bf16,
    const float* __restrict__ bias, int bias_mode,
    const float* __restrict__ madd, int mask_ld,
    float* __restrict__ rowsum, int rs_mode, int rs_ld, int xcd_mode,
    float scale, int K) {
    __shared__ __align__(16) u16 SMEM[2][256 * 32];  // As 128*32 + Bs 128*32 per buf
    int bxi, byi, bzi;
    if (xcd_mode == 1) {
        const int xcd = blockIdx.x;                       // gridDim.x == 8
        const int s = blockIdx.y + (gridDim.y * blockIdx.z);  // gridDim.y==16 -> s in [0,64)
        bzi = xcd >> 1;
        byi = (xcd & 1) * 8 + (s >> 3);
        bxi = s & 7;
    } else {
        bxi = blockIdx.x; byi = blockIdx.y; bzi = blockIdx.z;
    }
    const int bz = bzi;
    const u16* Ab = A + (long)bz * sA;
    const u16* Bb = B + (long)bz * sB;
    const int tm = byi * 128, tn = bxi * 128;
    const int tid = threadIdx.x, wave = tid >> 6, lane = tid & 63;
    const int wm = (wave >> 1) * 64, wn = (wave & 1) * 64;
    const int lr = lane >> 2, c = lane & 3;
    const int fm = lane & 15, fq = lane >> 4;

    f32x4 acc[4][4];
#pragma unroll
    for (int i = 0; i < 4; i++)
#pragma unroll
        for (int j = 0; j < 4; j++) acc[i][j] = (f32x4){0.f, 0.f, 0.f, 0.f};

    const int T = K >> 5;

    auto stage = [&](int t, int buf) {
        u16* As = &SMEM[buf][0];
        u16* Bs = &SMEM[buf][128 * 32];
#pragma unroll
        for (int r = 0; r < 2; r++) {
            const int rl = r * 64 + wave * 16;
            const int row = rl + lr;
            const int kc = (t << 5) + ((c ^ ((row ^ (row >> 2)) & 3)) << 3);
            const u16* ga = Ab + (long)(tm + row) * lda + kc;
            const u16* gb = Bb + (long)(tn + row) * ldb + kc;
            __builtin_amdgcn_global_load_lds((const __attribute__((address_space(1))) void*)ga,
                                             (__attribute__((address_space(3))) void*)&As[rl * 32],
                                             16, 0, 0);
            __builtin_amdgcn_global_load_lds((const __attribute__((address_space(1))) void*)gb,
                                             (__attribute__((address_space(3))) void*)&Bs[rl * 32],
                                             16, 0, 0);
        }
    };

    stage(0, 0);
    __syncthreads();
    for (int t = 0; t < T; t++) {
        const int cur = t & 1;
        if (t + 1 < T) stage(t + 1, cur ^ 1);
        const u16* As = &SMEM[cur][0];
        const u16* Bs = &SMEM[cur][128 * 32];
        bf16x8 af[4], bfr[4];
#pragma unroll
        for (int i = 0; i < 4; i++) {
            int row = wm + i * 16 + fm;
            af[i] = *(const bf16x8*)&As[row * 32 + ((fq ^ ((row ^ (row >> 2)) & 3)) << 3)];
        }
#pragma unroll
        for (int j = 0; j < 4; j++) {
            int row = wn + j * 16 + fm;
            bfr[j] = *(const bf16x8*)&Bs[row * 32 + ((fq ^ ((row ^ (row >> 2)) & 3)) << 3)];
        }
#pragma unroll
        for (int i = 0; i < 4; i++)
#pragma unroll
            for (int j = 0; j < 4; j++)
                acc[i][j] = __builtin_amdgcn_mfma_f32_16x16x32_bf16(af[i], bfr[j], acc[i][j], 0, 0, 0);
        if (t + 1 < T) __syncthreads();
    }
    __syncthreads();

    float* EP = (float*)&SMEM[0][0] + wave * 1088;
    const int row16 = lane >> 2, cb = (lane & 3) * 16;
    float4 bc[4];
    if (bias_mode == 1) {
#pragma unroll
        for (int q = 0; q < 4; q++) bc[q] = *(const float4*)&bias[tn + wn + cb + q * 4];
    }
#pragma unroll
    for (int i = 0; i < 4; i++) {
#pragma unroll
        for (int j = 0; j < 4; j++)
#pragma unroll
            for (int r = 0; r < 4; r++)
                EP[(fq * 4 + r) * 68 + j * 16 + fm] = acc[i][j][r];
        const long grow = tm + wm + i * 16 + row16;
        float rb = (bias_mode == 2) ? bias[grow] : 0.f;
        float4 t4[4];
#pragma unroll
        for (int q = 0; q < 4; q++) {
            float4 v = *(const float4*)&EP[row16 * 68 + cb + q * 4];
            v.x = v.x * scale + rb; v.y = v.y * scale + rb;
            v.z = v.z * scale + rb; v.w = v.w * scale + rb;
            if (bias_mode == 1) { v.x += bc[q].x; v.y += bc[q].y; v.z += bc[q].z; v.w += bc[q].w; }
            if (madd) {
                float4 m4 = *(const float4*)&madd[grow * mask_ld + tn + wn + cb + q * 4];
                v.x += m4.x; v.y += m4.y; v.z += m4.z; v.w += m4.w;
            }
            t4[q] = v;
        }
        if (rs_mode == 1) {
            float s = 0.f;
#pragma unroll
            for (int q = 0; q < 4; q++) {
                t4[q].x = __expf(t4[q].x); t4[q].y = __expf(t4[q].y);
                t4[q].z = __expf(t4[q].z); t4[q].w = __expf(t4[q].w);
                s += t4[q].x + t4[q].y + t4[q].z + t4[q].w;
            }
            s += __shfl_xor(s, 1);
            s += __shfl_xor(s, 2);
            if ((lane & 3) == 0) atomicAdd(&rowsum[(long)bz * rs_ld + grow], s);
        } else if (rs_mode == 2) {
            float inv = 1.f / rowsum[(long)bz * rs_ld + grow];
#pragma unroll
            for (int q = 0; q < 4; q++) {
                t4[q].x *= inv; t4[q].y *= inv; t4[q].z *= inv; t4[q].w *= inv;
            }
        }
        if (c_bf16) {
            u16* dst = (u16*)C + (long)bz * sC + grow * ldc + tn + wn + cb;
            uint4 o0 = {pack2(t4[0].x, t4[0].y), pack2(t4[0].z, t4[0].w),
                        pack2(t4[1].x, t4[1].y), pack2(t4[1].z, t4[1].w)};
            uint4 o1 = {pack2(t4[2].x, t4[2].y), pack2(t4[2].z, t4[2].w),
                        pack2(t4[3].x, t4[3].y), pack2(t4[3].z, t4[3].w)};
            *(uint4*)dst = o0;
            *(uint4*)(dst + 8) = o1;
        } else {
            float* dst = (float*)C + (long)bz * sC + grow * ldc + tn + wn + cb;
#pragma unroll
            for (int q = 0; q < 4; q++) *(float4*)(dst + q * 4) = t4[q];
        }
    }
}

extern "C" void kernel_launch(void* const* d_in, const int* in_sizes, int n_in,
                              void* d_out, int out_size, void* d_ws, size_t ws_size,
                              hipStream_t stream) {
    const float* x    = (const float*)d_in[0];
    const float* mask = (const float*)d_in[1];
    const float* Wq   = (const float*)d_in[2];
    const float* bq   = (const float*)d_in[3];
    const float* Wk   = (const float*)d_in[4];
    const float* bk   = (const float*)d_in[5];
    const float* Wv   = (const float*)d_in[6];
    const float* bv   = (const float*)d_in[7];
    float* out = (float*)d_out;

    const int B = 4, S = 2048, D = 1024;
    const long MS = (long)B * S;  // 8192

    size_t need = (size_t)MS * D * 2 + (size_t)(2 * D) * D * 2 + (size_t)D * D * 2
                + (size_t)(2 * D) * 4 + (size_t)MS * (2 * D) * 2 + (size_t)D * MS * 2
                + (size_t)B * S * S * 2 + (size_t)B * S * 4 + (size_t)S * S * 2;
    if (ws_size < need) return;

    char* ws = (char*)d_ws;
    u16*  xb   = (u16*)ws;  ws += (long)MS * D * 2;
    u16*  wqkt = (u16*)ws;  ws += (long)(2 * D) * D * 2;
    u16*  wvt  = (u16*)ws;  ws += (long)D * D * 2;
    float* bqk = (float*)ws; ws += (long)(2 * D) * 4;
    u16*  QK   = (u16*)ws;  ws += (long)MS * (2 * D) * 2;
    u16*  VT   = (u16*)ws;  ws += (long)D * MS * 2;
    u16*  sc   = (u16*)ws;  ws += (long)B * S * S * 2;
    float* rsum = (float*)ws; ws += (long)B * S * 4;
    u16*  maskb = (u16*)ws; ws += (long)S * S * 2;

    const float SCALE = 0.03125f;  // 1/sqrt(1024)

    hipMemsetAsync(rsum, 0, (size_t)B * S * 4, stream);

    convert_bf16_kernel<<<(int)((MS * D / 4 + 255) / 256), 256, 0, stream>>>(x, xb, (int)(MS * D / 4));
    // mask fp32 -> bf16 (16.8 MB -> 8.4 MB; it was ~67 MB of the scores FETCH)
    convert_bf16_kernel<<<(int)(((long)S * S / 4 + 255) / 256), 256, 0, stream>>>(
        mask, maskb, (int)((long)S * S / 4));
    transpose3_to_bf16_kernel<<<dim3(32, 32, 3), dim3(32, 8), 0, stream>>>(
        Wq, Wk, Wv, wqkt, wqkt + (long)D * D, wvt, D);
    concat_bias_kernel<<<8, 256, 0, stream>>>(bq, bk, bqk, D);

    // QK projection: [8192, 2048] bf16, 256x256 pipelined tiles -> grid (8, 32), 1 block/CU
    gemm256_kernel<<<dim3(2 * D / 256, (int)(MS / 256), 1), 512, 0, stream>>>(
        xb, D, 0, wqkt, D, 0, QK, 2 * D, 0, 1, bqk, 1, nullptr, 0,
        nullptr, 0, 0, 1.0f, D);
    // V^T [1024, 8192] bf16: 128^2 tiles, grid (64, 8)
    gemm_bt_kernel<<<dim3((int)(MS / 128), D / 128, 1), 256, 0, stream>>>(
        wvt, D, 0, xb, D, 0, VT, (int)MS, 0, 1, bv, 2, nullptr, 0,
        nullptr, 0, 0, 0, 1.0f, D);

    // scores: exp((Q.K^T)*scale + mask) -> bf16, rowsum accumulated (softmax numerator)
    // 256x256 pipelined tiles -> grid (8, 8, 4) = 256 blocks; mask read as bf16
    gemm256_kernel<<<dim3(S / 256, S / 256, B), 512, 0, stream>>>(
        QK, 2 * D, (long)S * 2 * D, QK + D, 2 * D, (long)S * 2 * D, sc, S, (long)S * S, 1,
        nullptr, 0, maskb, S, rsum, 1, S, SCALE, D);

    // PV: out = (exp-scores @ VT^T) / rowsum  (softmax denominator fused in epilogue).
    // xcd_mode=1 (grid (8,16,4)): each XCD owns one batch-half (8q x 8d, single z)
    // -> per-XCD co-resident working set 8 MB instead of ~20 MB.
    gemm_bt_kernel<<<dim3(D / 128, S / 128, B), 256, 0, stream>>>(
        sc, S, (long)S * S, VT, (int)MS, (long)S, out, D, (long)S * D, 0,
        nullptr, 0, nullptr, 0, rsum, 2, S, 1, 1.0f, S);
}

// Round 6
// 277.530 us; speedup vs baseline: 1.1232x; 1.0146x over previous
//
#include <hip/hip_runtime.h>

typedef unsigned short u16;
typedef unsigned int u32;

typedef __attribute__((ext_vector_type(8))) short bf16x8;
typedef __attribute__((ext_vector_type(4))) float f32x4;

static __device__ __forceinline__ u16 f2bf(float f) {
    u32 u = __float_as_uint(f);
    u32 r = (u + 0x7FFFu + ((u >> 16) & 1u)) >> 16;
    return (u16)r;
}
static __device__ __forceinline__ float bf2f(u16 h) {
    return __uint_as_float(((u32)h) << 16);
}
static __device__ __forceinline__ u32 pack2(float a, float b) {
    return (u32)f2bf(a) | ((u32)f2bf(b) << 16);
}

// ===================== fused prep: one dispatch for all preprocessing =====================
// flat block ranges: [0,8192) x->bf16 | [8192,12288) mask->bf16 | [12288,15360) W transpose
//                    [15360,15368) bias concat | [15368,15400) rsum zero
__global__ __launch_bounds__(256) void prep_kernel(
    const float* __restrict__ x, u16* __restrict__ xb,
    const float* __restrict__ mask, u16* __restrict__ maskb,
    const float* __restrict__ Wq, const float* __restrict__ Wk, const float* __restrict__ Wv,
    u16* __restrict__ T0, u16* __restrict__ T1, u16* __restrict__ T2,
    const float* __restrict__ bq, const float* __restrict__ bk,
    float* __restrict__ bqk, float* __restrict__ rsum) {
    const int D = 1024;
    int bid = blockIdx.x;
    const int tid = threadIdx.x;
    if (bid < 8192) {  // x fp32 -> bf16, vectorized
        long i = (long)bid * 256 + tid;
        float4 v = ((const float4*)x)[i];
        ushort4 o; o.x = f2bf(v.x); o.y = f2bf(v.y); o.z = f2bf(v.z); o.w = f2bf(v.w);
        ((ushort4*)xb)[i] = o;
        return;
    }
    bid -= 8192;
    if (bid < 4096) {  // mask fp32 -> bf16 (fp32 mask was ~67 MB of scores FETCH)
        long i = (long)bid * 256 + tid;
        float4 v = ((const float4*)mask)[i];
        ushort4 o; o.x = f2bf(v.x); o.y = f2bf(v.y); o.z = f2bf(v.z); o.w = f2bf(v.w);
        ((ushort4*)maskb)[i] = o;
        return;
    }
    bid -= 4096;
    if (bid < 3072) {  // 3x W [K,N] fp32 -> W^T [N,K] bf16
        __shared__ float t[32][33];
        const int z = bid >> 10, loc = bid & 1023;
        const int bx = loc & 31, by = loc >> 5;
        const float* W = (z == 0) ? Wq : (z == 1) ? Wk : Wv;
        u16* WT = (z == 0) ? T0 : (z == 1) ? T1 : T2;
        const int tx = tid & 31, ty = tid >> 5;
#pragma unroll
        for (int i = ty; i < 32; i += 8)
            t[i][tx] = W[(long)(by * 32 + i) * D + bx * 32 + tx];
        __syncthreads();
#pragma unroll
        for (int i = ty; i < 32; i += 8)
            WT[(long)(bx * 32 + i) * D + by * 32 + tx] = f2bf(t[tx][i]);
        return;
    }
    bid -= 3072;
    if (bid < 8) {  // bias concat [bq|bk]
        int i = bid * 256 + tid;
        bqk[i] = (i < 1024) ? bq[i] : bk[i - 1024];
        return;
    }
    bid -= 8;
    rsum[bid * 256 + tid] = 0.f;  // rowsum zero (replaces hipMemsetAsync)
}

// =====================================================================================
// Unified 128x128-tile GEMM core, BK=32, double-buffered LDS (32 KB), __syncthreads
// per K-step (m97-proven structure; R5's counted-vmcnt triple-buffer RACED on replay
// -- post-timing divergence -- and is reverted per the "sync-structure edits are new
// templates" rule). 4 blocks/CU via __launch_bounds__(256,4).
// C[m][n] = sum_k A[m][k]*B[n][k] (both row-major over k).
// bias_mode: 1 col-bias, 2 row-bias. madd: optional bf16 additive mask.
// rs_mode: 1 softmax numerator (exp + atomic rowsum; safe without max-sub since
// |scores*scale+mask| small), 2 divide by rowsum.
// =====================================================================================
static __device__ __forceinline__ void gemm_core(
    u16* __restrict__ SM,  // 2 * 256*32 u16 LDS
    const u16* __restrict__ Ab, int lda,
    const u16* __restrict__ Bb, int ldb,
    void* __restrict__ Cb, int ldc, int c_bf16,
    const float* __restrict__ bias, int bias_mode,
    const u16* __restrict__ madd, int mask_ld,
    float* __restrict__ rowsum, int rs_mode,
    float scale, int K, int tm, int tn) {
    const int tid = threadIdx.x, wave = tid >> 6, lane = tid & 63;
    const int wm = (wave >> 1) * 64, wn = (wave & 1) * 64;
    const int lr = lane >> 2, c = lane & 3;
    const int fm = lane & 15, fq = lane >> 4;

    f32x4 acc[4][4];
#pragma unroll
    for (int i = 0; i < 4; i++)
#pragma unroll
        for (int j = 0; j < 4; j++) acc[i][j] = (f32x4){0.f, 0.f, 0.f, 0.f};

    const int T = K >> 5;

    auto stage = [&](int t, int buf) {
        u16* As = SM + buf * 8192;
        u16* Bs = As + 4096;
#pragma unroll
        for (int r = 0; r < 2; r++) {
            const int rl = r * 64 + wave * 16;
            const int row = rl + lr;
            const int kc = (t << 5) + ((c ^ ((row ^ (row >> 2)) & 3)) << 3);
            const u16* ga = Ab + (long)(tm + row) * lda + kc;
            const u16* gb = Bb + (long)(tn + row) * ldb + kc;
            __builtin_amdgcn_global_load_lds((const __attribute__((address_space(1))) void*)ga,
                                             (__attribute__((address_space(3))) void*)&As[rl * 32],
                                             16, 0, 0);
            __builtin_amdgcn_global_load_lds((const __attribute__((address_space(1))) void*)gb,
                                             (__attribute__((address_space(3))) void*)&Bs[rl * 32],
                                             16, 0, 0);
        }
    };

    stage(0, 0);
    __syncthreads();
    for (int t = 0; t < T; t++) {
        const int cur = t & 1;
        if (t + 1 < T) stage(t + 1, cur ^ 1);
        const u16* As = SM + cur * 8192;
        const u16* Bs = As + 4096;
        bf16x8 af[4], bfr[4];
#pragma unroll
        for (int i = 0; i < 4; i++) {
            int row = wm + i * 16 + fm;
            af[i] = *(const bf16x8*)&As[row * 32 + ((fq ^ ((row ^ (row >> 2)) & 3)) << 3)];
        }
#pragma unroll
        for (int j = 0; j < 4; j++) {
            int row = wn + j * 16 + fm;
            bfr[j] = *(const bf16x8*)&Bs[row * 32 + ((fq ^ ((row ^ (row >> 2)) & 3)) << 3)];
        }
#pragma unroll
        for (int i = 0; i < 4; i++)
#pragma unroll
            for (int j = 0; j < 4; j++)
                acc[i][j] = __builtin_amdgcn_mfma_f32_16x16x32_bf16(af[i], bfr[j], acc[i][j], 0, 0, 0);
        if (t + 1 < T) __syncthreads();
    }
    __syncthreads();

    // -------- epilogue: per-wave LDS transpose, fused bias/mask/exp/rowsum --------
    float* EP = (float*)SM + wave * 1088;
    const int row16 = lane >> 2, cb = (lane & 3) * 16;
    float4 bc[4];
    if (bias_mode == 1) {
#pragma unroll
        for (int q = 0; q < 4; q++) bc[q] = *(const float4*)&bias[tn + wn + cb + q * 4];
    }
#pragma unroll
    for (int i = 0; i < 4; i++) {
#pragma unroll
        for (int j = 0; j < 4; j++)
#pragma unroll
            for (int r = 0; r < 4; r++)
                EP[(fq * 4 + r) * 68 + j * 16 + fm] = acc[i][j][r];
        const long grow = tm + wm + i * 16 + row16;
        float rb = (bias_mode == 2) ? bias[grow] : 0.f;
        float4 t4[4];
#pragma unroll
        for (int q = 0; q < 4; q++) {
            float4 v = *(const float4*)&EP[row16 * 68 + cb + q * 4];
            v.x = v.x * scale + rb; v.y = v.y * scale + rb;
            v.z = v.z * scale + rb; v.w = v.w * scale + rb;
            if (bias_mode == 1) { v.x += bc[q].x; v.y += bc[q].y; v.z += bc[q].z; v.w += bc[q].w; }
            if (madd) {
                ushort4 m4 = *(const ushort4*)&madd[grow * mask_ld + tn + wn + cb + q * 4];
                v.x += bf2f(m4.x); v.y += bf2f(m4.y); v.z += bf2f(m4.z); v.w += bf2f(m4.w);
            }
            t4[q] = v;
        }
        if (rs_mode == 1) {
            float s = 0.f;
#pragma unroll
            for (int q = 0; q < 4; q++) {
                t4[q].x = __expf(t4[q].x); t4[q].y = __expf(t4[q].y);
                t4[q].z = __expf(t4[q].z); t4[q].w = __expf(t4[q].w);
                s += t4[q].x + t4[q].y + t4[q].z + t4[q].w;
            }
            s += __shfl_xor(s, 1);
            s += __shfl_xor(s, 2);
            if ((lane & 3) == 0) atomicAdd(&rowsum[grow], s);
        } else if (rs_mode == 2) {
            float inv = 1.f / rowsum[grow];
#pragma unroll
            for (int q = 0; q < 4; q++) {
                t4[q].x *= inv; t4[q].y *= inv; t4[q].z *= inv; t4[q].w *= inv;
            }
        }
        if (c_bf16) {
            u16* dst = (u16*)Cb + grow * ldc + tn + wn + cb;
            uint4 o0 = {pack2(t4[0].x, t4[0].y), pack2(t4[0].z, t4[0].w),
                        pack2(t4[1].x, t4[1].y), pack2(t4[1].z, t4[1].w)};
            uint4 o1 = {pack2(t4[2].x, t4[2].y), pack2(t4[2].z, t4[2].w),
                        pack2(t4[3].x, t4[3].y), pack2(t4[3].z, t4[3].w)};
            *(uint4*)dst = o0;
            *(uint4*)(dst + 8) = o1;
        } else {
            float* dst = (float*)Cb + grow * ldc + tn + wn + cb;
#pragma unroll
            for (int q = 0; q < 4; q++) *(float4*)(dst + q * 4) = t4[q];
        }
    }
}

// ---- QK projection + V^T in ONE dispatch (heterogeneous flat grid, 1536 blocks) ----
// id < 1024: QK tile (64 m-tiles x 16 n-tiles): QK[8192,2048] = xb @ wqkt^T + bqk
// id >= 1024: VT tile (8 m-tiles x 64 n-tiles): VT[1024,8192] = wvt @ xb^T + bv(row)
__global__ __launch_bounds__(256, 4) void gemm_qkvt_kernel(
    const u16* __restrict__ xb, const u16* __restrict__ wqkt, const u16* __restrict__ wvt,
    u16* __restrict__ QK, u16* __restrict__ VT,
    const float* __restrict__ bqk, const float* __restrict__ bv) {
    __shared__ __align__(16) u16 SM[2][256 * 32];
    const int D = 1024, MS = 8192;
    const int id = blockIdx.x;
    if (id < 1024) {
        gemm_core(&SM[0][0], xb, D, wqkt, D, QK, 2 * D, 1, bqk, 1, nullptr, 0,
                  nullptr, 0, 1.0f, D, (id >> 4) * 128, (id & 15) * 128);
    } else {
        const int f = id - 1024;
        gemm_core(&SM[0][0], wvt, D, xb, D, VT, MS, 1, bv, 2, nullptr, 0,
                  nullptr, 0, 1.0f, D, (f >> 6) * 128, (f & 63) * 128);
    }
}

// ---- scores: sc = exp((Q.K^T)*scale + mask) bf16, rowsum accumulated ----
// 1024 linear blocks, bijective XCD-ownership map: xcd = lin&7 owns (bz=xcd>>1,
// q-half=xcd&1); within it k-tile fastest -> per-XCD B-panel set ~4 MB (L2-resident),
// A-panel reused across 16 consecutive blocks.
__global__ __launch_bounds__(256, 4) void gemm_sc_kernel(
    const u16* __restrict__ QK, u16* __restrict__ sc,
    const u16* __restrict__ maskb, float* __restrict__ rsum, float scale) {
    __shared__ __align__(16) u16 SM[2][256 * 32];
    const int S = 2048, D = 1024;
    const int lin = blockIdx.x;
    const int xcd = lin & 7, r = lin >> 3;
    const int bx = r & 15, ylo = (r >> 4) & 7;
    const int bz = xcd >> 1, by = (xcd & 1) * 8 + ylo;
    gemm_core(&SM[0][0],
              QK + (long)bz * S * 2 * D, 2 * D,
              QK + D + (long)bz * S * 2 * D, 2 * D,
              sc + (long)bz * S * S, S, 1, nullptr, 0,
              maskb, S, rsum + (long)bz * S, 1,
              scale, D, by * 128, bx * 128);
}

// ---- PV: out = (exp-scores @ VT^T) / rowsum; XCD owns one batch-half (R4 map,
// FETCH 82 -> 33 MB validated) ----
__global__ __launch_bounds__(256, 4) void gemm_pv_kernel(
    const u16* __restrict__ sc, const u16* __restrict__ VT,
    float* __restrict__ out, const float* __restrict__ rsum) {
    __shared__ __align__(16) u16 SM[2][256 * 32];
    const int S = 2048, D = 1024, MS = 8192;
    const int xcd = blockIdx.x;                       // gridDim.x == 8
    const int s = blockIdx.y + 16 * blockIdx.z;       // [0,64)
    const int bz = xcd >> 1;
    const int byi = (xcd & 1) * 8 + (s >> 3);         // q-tile
    const int bxi = s & 7;                            // d-tile
    gemm_core(&SM[0][0],
              sc + (long)bz * S * S, S,
              VT + (long)bz * S, MS,
              out + (long)bz * S * D, D, 0, nullptr, 0,
              nullptr, 0, (float*)(rsum + (long)bz * S), 2,
              1.0f, S, byi * 128, bxi * 128);
}

extern "C" void kernel_launch(void* const* d_in, const int* in_sizes, int n_in,
                              void* d_out, int out_size, void* d_ws, size_t ws_size,
                              hipStream_t stream) {
    const float* x    = (const float*)d_in[0];
    const float* mask = (const float*)d_in[1];
    const float* Wq   = (const float*)d_in[2];
    const float* bq   = (const float*)d_in[3];
    const float* Wk   = (const float*)d_in[4];
    const float* bk   = (const float*)d_in[5];
    const float* Wv   = (const float*)d_in[6];
    const float* bv   = (const float*)d_in[7];
    float* out = (float*)d_out;

    const int B = 4, S = 2048, D = 1024;
    const long MS = (long)B * S;  // 8192

    size_t need = (size_t)MS * D * 2 + (size_t)(2 * D) * D * 2 + (size_t)D * D * 2
                + (size_t)(2 * D) * 4 + (size_t)MS * (2 * D) * 2 + (size_t)D * MS * 2
                + (size_t)B * S * S * 2 + (size_t)B * S * 4 + (size_t)S * S * 2;
    if (ws_size < need) return;

    char* ws = (char*)d_ws;
    u16*  xb   = (u16*)ws;  ws += (long)MS * D * 2;
    u16*  wqkt = (u16*)ws;  ws += (long)(2 * D) * D * 2;
    u16*  wvt  = (u16*)ws;  ws += (long)D * D * 2;
    float* bqk = (float*)ws; ws += (long)(2 * D) * 4;
    u16*  QK   = (u16*)ws;  ws += (long)MS * (2 * D) * 2;
    u16*  VT   = (u16*)ws;  ws += (long)D * MS * 2;
    u16*  sc   = (u16*)ws;  ws += (long)B * S * S * 2;
    float* rsum = (float*)ws; ws += (long)B * S * 4;
    u16*  maskb = (u16*)ws; ws += (long)S * S * 2;

    const float SCALE = 0.03125f;  // 1/sqrt(1024)

    // 1) fused prep (x/mask->bf16, W transposes, bias concat, rsum zero)
    prep_kernel<<<15400, 256, 0, stream>>>(x, xb, mask, maskb, Wq, Wk, Wv,
                                           wqkt, wqkt + (long)D * D, wvt,
                                           bq, bk, bqk, rsum);
    // 2) QK projection + V^T, one dispatch (1536 blocks)
    gemm_qkvt_kernel<<<1536, 256, 0, stream>>>(xb, wqkt, wvt, QK, VT, bqk, bv);
    // 3) scores (softmax numerator fused), 1024 blocks, XCD-owned regions
    gemm_sc_kernel<<<1024, 256, 0, stream>>>(QK, sc, maskb, rsum, SCALE);
    // 4) PV (softmax denominator fused), grid (8,16,4), XCD-owned batch-halves
    gemm_pv_kernel<<<dim3(8, 16, 4), 256, 0, stream>>>(sc, VT, out, rsum);
}

// Round 7
// 262.882 us; speedup vs baseline: 1.1858x; 1.0557x over previous
//
#include <hip/hip_runtime.h>

typedef unsigned short u16;
typedef unsigned int u32;

typedef __attribute__((ext_vector_type(8))) short bf16x8;
typedef __attribute__((ext_vector_type(4))) float f32x4;

static __device__ __forceinline__ u16 f2bf(float f) {
    u32 u = __float_as_uint(f);
    u32 r = (u + 0x7FFFu + ((u >> 16) & 1u)) >> 16;
    return (u16)r;
}
static __device__ __forceinline__ float bf2f(u16 h) {
    return __uint_as_float(((u32)h) << 16);
}
static __device__ __forceinline__ u32 pack2(float a, float b) {
    return (u32)f2bf(a) | ((u32)f2bf(b) << 16);
}

// ===================== prep: x->bf16, W transposes, bias concat =====================
// flat ranges: [0,8192) x->bf16 | [8192,11264) W transpose | [11264,11272) bias concat
__global__ __launch_bounds__(256) void prep_kernel(
    const float* __restrict__ x, u16* __restrict__ xb,
    const float* __restrict__ Wq, const float* __restrict__ Wk, const float* __restrict__ Wv,
    u16* __restrict__ T0, u16* __restrict__ T1, u16* __restrict__ T2,
    const float* __restrict__ bq, const float* __restrict__ bk,
    float* __restrict__ bqk) {
    const int D = 1024;
    int bid = blockIdx.x;
    const int tid = threadIdx.x;
    if (bid < 8192) {  // x fp32 -> bf16, vectorized
        long i = (long)bid * 256 + tid;
        float4 v = ((const float4*)x)[i];
        ushort4 o; o.x = f2bf(v.x); o.y = f2bf(v.y); o.z = f2bf(v.z); o.w = f2bf(v.w);
        ((ushort4*)xb)[i] = o;
        return;
    }
    bid -= 8192;
    if (bid < 3072) {  // 3x W [K,N] fp32 -> W^T [N,K] bf16
        __shared__ float t[32][33];
        const int z = bid >> 10, loc = bid & 1023;
        const int bx = loc & 31, by = loc >> 5;
        const float* W = (z == 0) ? Wq : (z == 1) ? Wk : Wv;
        u16* WT = (z == 0) ? T0 : (z == 1) ? T1 : T2;
        const int tx = tid & 31, ty = tid >> 5;
#pragma unroll
        for (int i = ty; i < 32; i += 8)
            t[i][tx] = W[(long)(by * 32 + i) * D + bx * 32 + tx];
        __syncthreads();
#pragma unroll
        for (int i = ty; i < 32; i += 8)
            WT[(long)(bx * 32 + i) * D + by * 32 + tx] = f2bf(t[tx][i]);
        return;
    }
    bid -= 3072;
    {  // bias concat [bq|bk]
        int i = bid * 256 + tid;
        bqk[i] = (i < 1024) ? bq[i] : bk[i - 1024];
    }
}

// =====================================================================================
// 128x128-tile GEMM core, BK=32, double-buffered LDS (32 KB), __syncthreads per K-step
// (m97-proven structure). Used by the merged QK+VT dispatch (R6-measured 78.5 us).
// =====================================================================================
static __device__ __forceinline__ void gemm_core(
    u16* __restrict__ SM,  // 2 * 256*32 u16 LDS
    const u16* __restrict__ Ab, int lda,
    const u16* __restrict__ Bb, int ldb,
    void* __restrict__ Cb, int ldc, int c_bf16,
    const float* __restrict__ bias, int bias_mode,
    float scale, int K, int tm, int tn) {
    const int tid = threadIdx.x, wave = tid >> 6, lane = tid & 63;
    const int wm = (wave >> 1) * 64, wn = (wave & 1) * 64;
    const int lr = lane >> 2, c = lane & 3;
    const int fm = lane & 15, fq = lane >> 4;

    f32x4 acc[4][4];
#pragma unroll
    for (int i = 0; i < 4; i++)
#pragma unroll
        for (int j = 0; j < 4; j++) acc[i][j] = (f32x4){0.f, 0.f, 0.f, 0.f};

    const int T = K >> 5;

    auto stage = [&](int t, int buf) {
        u16* As = SM + buf * 8192;
        u16* Bs = As + 4096;
#pragma unroll
        for (int r = 0; r < 2; r++) {
            const int rl = r * 64 + wave * 16;
            const int row = rl + lr;
            const int kc = (t << 5) + ((c ^ ((row ^ (row >> 2)) & 3)) << 3);
            const u16* ga = Ab + (long)(tm + row) * lda + kc;
            const u16* gb = Bb + (long)(tn + row) * ldb + kc;
            __builtin_amdgcn_global_load_lds((const __attribute__((address_space(1))) void*)ga,
                                             (__attribute__((address_space(3))) void*)&As[rl * 32],
                                             16, 0, 0);
            __builtin_amdgcn_global_load_lds((const __attribute__((address_space(1))) void*)gb,
                                             (__attribute__((address_space(3))) void*)&Bs[rl * 32],
                                             16, 0, 0);
        }
    };

    stage(0, 0);
    __syncthreads();
    for (int t = 0; t < T; t++) {
        const int cur = t & 1;
        if (t + 1 < T) stage(t + 1, cur ^ 1);
        const u16* As = SM + cur * 8192;
        const u16* Bs = As + 4096;
        bf16x8 af[4], bfr[4];
#pragma unroll
        for (int i = 0; i < 4; i++) {
            int row = wm + i * 16 + fm;
            af[i] = *(const bf16x8*)&As[row * 32 + ((fq ^ ((row ^ (row >> 2)) & 3)) << 3)];
        }
#pragma unroll
        for (int j = 0; j < 4; j++) {
            int row = wn + j * 16 + fm;
            bfr[j] = *(const bf16x8*)&Bs[row * 32 + ((fq ^ ((row ^ (row >> 2)) & 3)) << 3)];
        }
#pragma unroll
        for (int i = 0; i < 4; i++)
#pragma unroll
            for (int j = 0; j < 4; j++)
                acc[i][j] = __builtin_amdgcn_mfma_f32_16x16x32_bf16(af[i], bfr[j], acc[i][j], 0, 0, 0);
        if (t + 1 < T) __syncthreads();
    }
    __syncthreads();

    // epilogue: per-wave LDS transpose, bias, bf16 store
    float* EP = (float*)SM + wave * 1088;
    const int row16 = lane >> 2, cb = (lane & 3) * 16;
    float4 bc[4];
    if (bias_mode == 1) {
#pragma unroll
        for (int q = 0; q < 4; q++) bc[q] = *(const float4*)&bias[tn + wn + cb + q * 4];
    }
#pragma unroll
    for (int i = 0; i < 4; i++) {
#pragma unroll
        for (int j = 0; j < 4; j++)
#pragma unroll
            for (int r = 0; r < 4; r++)
                EP[(fq * 4 + r) * 68 + j * 16 + fm] = acc[i][j][r];
        const long grow = tm + wm + i * 16 + row16;
        float rb = (bias_mode == 2) ? bias[grow] : 0.f;
        float4 t4[4];
#pragma unroll
        for (int q = 0; q < 4; q++) {
            float4 v = *(const float4*)&EP[row16 * 68 + cb + q * 4];
            v.x = v.x * scale + rb; v.y = v.y * scale + rb;
            v.z = v.z * scale + rb; v.w = v.w * scale + rb;
            if (bias_mode == 1) { v.x += bc[q].x; v.y += bc[q].y; v.z += bc[q].z; v.w += bc[q].w; }
            t4[q] = v;
        }
        u16* dst = (u16*)Cb + grow * ldc + tn + wn + cb;
        uint4 o0 = {pack2(t4[0].x, t4[0].y), pack2(t4[0].z, t4[0].w),
                    pack2(t4[1].x, t4[1].y), pack2(t4[1].z, t4[1].w)};
        uint4 o1 = {pack2(t4[2].x, t4[2].y), pack2(t4[2].z, t4[2].w),
                    pack2(t4[3].x, t4[3].y), pack2(t4[3].z, t4[3].w)};
        *(uint4*)dst = o0;
        *(uint4*)(dst + 8) = o1;
    }
}

// ---- QK projection + V^T + mask->bf16 + rsum zero, ONE dispatch (5664 blocks) ----
// [0,1024): QK tiles | [1024,1536): VT tiles | [1536,5632): mask convert | [5632,5664): rsum=0
// Light blocks sit at the grid tail and overlap the GEMM drain.
__global__ __launch_bounds__(256, 4) void gemm_qkvt_kernel(
    const u16* __restrict__ xb, const u16* __restrict__ wqkt, const u16* __restrict__ wvt,
    u16* __restrict__ QK, u16* __restrict__ VT,
    const float* __restrict__ bqk, const float* __restrict__ bv,
    const float* __restrict__ mask, u16* __restrict__ maskb, float* __restrict__ rsum) {
    __shared__ __align__(16) u16 SM[2][256 * 32];
    const int D = 1024, MS = 8192;
    const int id = blockIdx.x;
    if (id < 1024) {
        gemm_core(&SM[0][0], xb, D, wqkt, D, QK, 2 * D, 1, bqk, 1,
                  1.0f, D, (id >> 4) * 128, (id & 15) * 128);
    } else if (id < 1536) {
        const int f = id - 1024;
        gemm_core(&SM[0][0], wvt, D, xb, D, VT, MS, 1, bv, 2,
                  1.0f, D, (f >> 6) * 128, (f & 63) * 128);
    } else if (id < 5632) {
        long i = (long)(id - 1536) * 256 + threadIdx.x;
        float4 v = ((const float4*)mask)[i];
        ushort4 o; o.x = f2bf(v.x); o.y = f2bf(v.y); o.z = f2bf(v.z); o.w = f2bf(v.w);
        ((ushort4*)maskb)[i] = o;
    } else {
        rsum[(id - 5632) * 256 + threadIdx.x] = 0.f;
    }
}

// =====================================================================================
// sc: 256x256-tile, BK=64, 8-wave pipelined counted-vmcnt GEMM (R4-proven verbatim).
// exp((Q.K^T)*scale + mask[bf16]) -> bf16, fp32 rowsum via 4-lane-reduced atomics
// (safe without max-subtraction: |scores*scale + mask| small).
// =====================================================================================
__global__ __launch_bounds__(512, 2) void gemm256_kernel(
    const u16* __restrict__ A, int lda, long sA,
    const u16* __restrict__ B, int ldb, long sB,
    void* __restrict__ C, int ldc, long sC,
    const u16* __restrict__ madd, int mask_ld,
    float* __restrict__ rowsum, int rs_ld,
    float scale, int K) {
    __shared__ __align__(16) u16 SMEM[2][2 * 256 * 64];
    const int bz = blockIdx.z;
    const u16* Ab = A + (long)bz * sA;
    const u16* Bb = B + (long)bz * sB;
    int bx, by;
    {
        const int gx = gridDim.x;
        int flat = blockIdx.y * gx + blockIdx.x;
        const int cpx = (gx * gridDim.y) >> 3;
        flat = (flat & 7) * cpx + (flat >> 3);
        bx = flat % gx;
        by = flat / gx;
    }
    const int tm = by << 8, tn = bx << 8;
    const int tid = threadIdx.x, wave = tid >> 6, lane = tid & 63;
    const int wq = wave & 3;
    const int wm = (wave >> 2) << 7;
    const int wn = wq << 6;
    const int fm = lane & 15, fq = lane >> 4;
    const int T = K >> 6;

    f32x4 acc[8][4];
#pragma unroll
    for (int i = 0; i < 8; i++)
#pragma unroll
        for (int j = 0; j < 4; j++) acc[i][j] = (f32x4){0.f, 0.f, 0.f, 0.f};

    const int srow = tid >> 3;
    const int sslot = tid & 7;

    auto stageA = [&](int t, int half) {
        u16* dst = &SMEM[t & 1][0];
        const int kb = t << 6;
#pragma unroll
        for (int blk = 0; blk < 2; blk++) {
            const int r0 = blk * 128 + half * 64;
            const int r = r0 + srow;
            const int gk = kb + ((sslot ^ (r & 7)) << 3);
            const u16* ga = Ab + (long)(tm + r) * lda + gk;
            __builtin_amdgcn_global_load_lds(
                (const __attribute__((address_space(1))) void*)ga,
                (__attribute__((address_space(3))) void*)&dst[(r0 + wave * 8) * 64], 16, 0, 0);
        }
    };
    auto stageB = [&](int t, int half) {
        u16* dst = &SMEM[t & 1][256 * 64];
        const int kb = t << 6;
#pragma unroll
        for (int blk = 0; blk < 2; blk++) {
            const int r0 = half * 128 + blk * 64;
            const int r = r0 + srow;
            const int g = ((r >> 5) & 3) * 64 + (r >> 7) * 32 + (r & 31);
            const int gk = kb + ((sslot ^ (r & 7)) << 3);
            const u16* gb = Bb + (long)(tn + g) * ldb + gk;
            __builtin_amdgcn_global_load_lds(
                (const __attribute__((address_space(1))) void*)gb,
                (__attribute__((address_space(3))) void*)&dst[(r0 + wave * 8) * 64], 16, 0, 0);
        }
    };

    auto read_a4 = [&](const u16* Ls, bf16x8 (&d)[4][2], int base) {
#pragma unroll
        for (int i = 0; i < 4; i++) {
            const int ra = base + i * 16 + fm;
            const int sw = ra & 7;
#pragma unroll
            for (int kh = 0; kh < 2; kh++)
                d[i][kh] = *(const bf16x8*)&Ls[ra * 64 + (((kh * 4 + fq) ^ sw) << 3)];
        }
    };
    auto read_b2 = [&](const u16* Ls, bf16x8 (&d)[2][2], int base) {
#pragma unroll
        for (int j = 0; j < 2; j++) {
            const int rb = base + j * 16 + fm;
            const int sw = rb & 7;
#pragma unroll
            for (int kh = 0; kh < 2; kh++)
                d[j][kh] = *(const bf16x8*)&Ls[rb * 64 + (((kh * 4 + fq) ^ sw) << 3)];
        }
    };

    stageA(0, 0); stageB(0, 0); stageA(0, 1); stageB(0, 1);
    if (T > 1) {
        stageA(1, 0); stageB(1, 0); stageA(1, 1);
        asm volatile("s_waitcnt vmcnt(6)" ::: "memory");
    } else {
        asm volatile("s_waitcnt vmcnt(0)" ::: "memory");
    }
    __builtin_amdgcn_sched_barrier(0);
    __builtin_amdgcn_s_barrier();
    __builtin_amdgcn_sched_barrier(0);

    bf16x8 alo[4][2], ahi[4][2], blo[2][2], bhi[2][2];
    read_a4(&SMEM[0][0], alo, wm);
    read_b2(&SMEM[0][256 * 64], blo, wq * 32);

    for (int u = 0; u < T; ++u) {
        const u16* As = &SMEM[u & 1][0];
        const u16* Bs = &SMEM[u & 1][256 * 64];
        const u16* As2 = &SMEM[(u + 1) & 1][0];
        const u16* Bs2 = &SMEM[(u + 1) & 1][256 * 64];
        if (u + 1 < T) stageB(u + 1, 1);
        read_b2(Bs, bhi, 128 + wq * 32);
        __builtin_amdgcn_sched_barrier(0);
        __builtin_amdgcn_s_setprio(1);
#pragma unroll
        for (int kh = 0; kh < 2; kh++)
#pragma unroll
            for (int i = 0; i < 4; i++)
#pragma unroll
                for (int j = 0; j < 2; j++)
                    acc[i][j] = __builtin_amdgcn_mfma_f32_16x16x32_bf16(alo[i][kh], blo[j][kh], acc[i][j], 0, 0, 0);
        __builtin_amdgcn_s_setprio(0);
        __builtin_amdgcn_sched_barrier(0);
        __builtin_amdgcn_s_barrier();
        __builtin_amdgcn_sched_barrier(0);
        if (u + 2 < T) stageA(u + 2, 0);
        read_a4(As, ahi, wm + 64);
        __builtin_amdgcn_sched_barrier(0);
        __builtin_amdgcn_s_setprio(1);
#pragma unroll
        for (int kh = 0; kh < 2; kh++)
#pragma unroll
            for (int i = 0; i < 4; i++)
#pragma unroll
                for (int j = 0; j < 2; j++)
                    acc[i][2 + j] = __builtin_amdgcn_mfma_f32_16x16x32_bf16(alo[i][kh], bhi[j][kh], acc[i][2 + j], 0, 0, 0);
        __builtin_amdgcn_s_setprio(0);
        __builtin_amdgcn_sched_barrier(0);
        __builtin_amdgcn_s_barrier();
        __builtin_amdgcn_sched_barrier(0);
        if (u + 2 < T) stageB(u + 2, 0);
        __builtin_amdgcn_sched_barrier(0);
        __builtin_amdgcn_s_setprio(1);
#pragma unroll
        for (int kh = 0; kh < 2; kh++)
#pragma unroll
            for (int i = 0; i < 4; i++)
#pragma unroll
                for (int j = 0; j < 2; j++)
                    acc[4 + i][j] = __builtin_amdgcn_mfma_f32_16x16x32_bf16(ahi[i][kh], blo[j][kh], acc[4 + i][j], 0, 0, 0);
        __builtin_amdgcn_s_setprio(0);
        __builtin_amdgcn_sched_barrier(0);
        __builtin_amdgcn_s_barrier();
        __builtin_amdgcn_sched_barrier(0);
        if (u + 2 < T) {
            stageA(u + 2, 1);
            asm volatile("s_waitcnt vmcnt(6)" ::: "memory");
        } else {
            asm volatile("s_waitcnt vmcnt(0)" ::: "memory");
        }
        __builtin_amdgcn_sched_barrier(0);
        __builtin_amdgcn_s_barrier();
        __builtin_amdgcn_sched_barrier(0);
        if (u + 1 < T) {
            read_a4(As2, alo, wm);
            read_b2(Bs2, blo, wq * 32);
        }
        __builtin_amdgcn_sched_barrier(0);
        __builtin_amdgcn_s_setprio(1);
#pragma unroll
        for (int kh = 0; kh < 2; kh++)
#pragma unroll
            for (int i = 0; i < 4; i++)
#pragma unroll
                for (int j = 0; j < 2; j++)
                    acc[4 + i][2 + j] = __builtin_amdgcn_mfma_f32_16x16x32_bf16(ahi[i][kh], bhi[j][kh], acc[4 + i][2 + j], 0, 0, 0);
        __builtin_amdgcn_s_setprio(0);
    }
    __syncthreads();

    float* EP = (float*)&SMEM[0][0] + wave * 1088;
    const int row16 = lane >> 2, cb = (lane & 3) * 16;
#pragma unroll
    for (int i = 0; i < 8; i++) {
#pragma unroll
        for (int j = 0; j < 4; j++)
#pragma unroll
            for (int r = 0; r < 4; r++)
                EP[(fq * 4 + r) * 68 + j * 16 + fm] = acc[i][j][r];
        const long grow = tm + wm + i * 16 + row16;
        float4 t4[4];
#pragma unroll
        for (int q = 0; q < 4; q++) {
            float4 v = *(const float4*)&EP[row16 * 68 + cb + q * 4];
            ushort4 m4 = *(const ushort4*)&madd[grow * mask_ld + tn + wn + cb + q * 4];
            v.x = v.x * scale + bf2f(m4.x); v.y = v.y * scale + bf2f(m4.y);
            v.z = v.z * scale + bf2f(m4.z); v.w = v.w * scale + bf2f(m4.w);
            t4[q] = v;
        }
        float s = 0.f;
#pragma unroll
        for (int q = 0; q < 4; q++) {
            t4[q].x = __expf(t4[q].x); t4[q].y = __expf(t4[q].y);
            t4[q].z = __expf(t4[q].z); t4[q].w = __expf(t4[q].w);
            s += t4[q].x + t4[q].y + t4[q].z + t4[q].w;
        }
        s += __shfl_xor(s, 1);
        s += __shfl_xor(s, 2);
        if ((lane & 3) == 0) atomicAdd(&rowsum[(long)bz * rs_ld + grow], s);
        u16* dst = (u16*)C + (long)bz * sC + grow * ldc + tn + wn + cb;
        uint4 o0 = {pack2(t4[0].x, t4[0].y), pack2(t4[0].z, t4[0].w),
                    pack2(t4[1].x, t4[1].y), pack2(t4[1].z, t4[1].w)};
        uint4 o1 = {pack2(t4[2].x, t4[2].y), pack2(t4[2].z, t4[2].w),
                    pack2(t4[3].x, t4[3].y), pack2(t4[3].z, t4[3].w)};
        *(uint4*)dst = o0;
        *(uint4*)(dst + 8) = o1;
    }
}

// ================= PV: 128x128-tile GEMM, BK=32 (R4-proven xcd map verbatim) =================
// grid (8,16,4): XCD = blockIdx.x owns one batch-half (8q x 8d, single z)
// -> per-XCD working set ~8 MB (FETCH 82 -> 33 MB validated in R4).
__global__ __launch_bounds__(256, 4) void gemm_pv_kernel(
    const u16* __restrict__ sc, const u16* __restrict__ VT,
    float* __restrict__ out, const float* __restrict__ rsum) {
    __shared__ __align__(16) u16 SMEM[2][256 * 32];
    const int S = 2048, D = 1024, MS = 8192;
    const int xcd = blockIdx.x;
    const int s = blockIdx.y + gridDim.y * blockIdx.z;
    const int bz = xcd >> 1;
    const int byi = (xcd & 1) * 8 + (s >> 3);
    const int bxi = s & 7;
    const u16* Ab = sc + (long)bz * S * S;
    const u16* Bb = VT + (long)bz * S;
    const float* rs = rsum + (long)bz * S;
    const int tm = byi * 128, tn = bxi * 128;
    const int tid = threadIdx.x, wave = tid >> 6, lane = tid & 63;
    const int wm = (wave >> 1) * 64, wn = (wave & 1) * 64;
    const int lr = lane >> 2, c = lane & 3;
    const int fm = lane & 15, fq = lane >> 4;

    f32x4 acc[4][4];
#pragma unroll
    for (int i = 0; i < 4; i++)
#pragma unroll
        for (int j = 0; j < 4; j++) acc[i][j] = (f32x4){0.f, 0.f, 0.f, 0.f};

    const int T = S >> 5;

    auto stage = [&](int t, int buf) {
        u16* As = &SMEM[buf][0];
        u16* Bs = &SMEM[buf][128 * 32];
#pragma unroll
        for (int r = 0; r < 2; r++) {
            const int rl = r * 64 + wave * 16;
            const int row = rl + lr;
            const int kc = (t << 5) + ((c ^ ((row ^ (row >> 2)) & 3)) << 3);
            const u16* ga = Ab + (long)(tm + row) * S + kc;
            const u16* gb = Bb + (long)(tn + row) * MS + kc;
            __builtin_amdgcn_global_load_lds((const __attribute__((address_space(1))) void*)ga,
                                             (__attribute__((address_space(3))) void*)&As[rl * 32],
                                             16, 0, 0);
            __builtin_amdgcn_global_load_lds((const __attribute__((address_space(1))) void*)gb,
                                             (__attribute__((address_space(3))) void*)&Bs[rl * 32],
                                             16, 0, 0);
        }
    };

    stage(0, 0);
    __syncthreads();
    for (int t = 0; t < T; t++) {
        const int cur = t & 1;
        if (t + 1 < T) stage(t + 1, cur ^ 1);
        const u16* As = &SMEM[cur][0];
        const u16* Bs = &SMEM[cur][128 * 32];
        bf16x8 af[4], bfr[4];
#pragma unroll
        for (int i = 0; i < 4; i++) {
            int row = wm + i * 16 + fm;
            af[i] = *(const bf16x8*)&As[row * 32 + ((fq ^ ((row ^ (row >> 2)) & 3)) << 3)];
        }
#pragma unroll
        for (int j = 0; j < 4; j++) {
            int row = wn + j * 16 + fm;
            bfr[j] = *(const bf16x8*)&Bs[row * 32 + ((fq ^ ((row ^ (row >> 2)) & 3)) << 3)];
        }
#pragma unroll
        for (int i = 0; i < 4; i++)
#pragma unroll
            for (int j = 0; j < 4; j++)
                acc[i][j] = __builtin_amdgcn_mfma_f32_16x16x32_bf16(af[i], bfr[j], acc[i][j], 0, 0, 0);
        if (t + 1 < T) __syncthreads();
    }
    __syncthreads();

    float* EP = (float*)&SMEM[0][0] + wave * 1088;
    const int row16 = lane >> 2, cb = (lane & 3) * 16;
#pragma unroll
    for (int i = 0; i < 4; i++) {
#pragma unroll
        for (int j = 0; j < 4; j++)
#pragma unroll
            for (int r = 0; r < 4; r++)
                EP[(fq * 4 + r) * 68 + j * 16 + fm] = acc[i][j][r];
        const long grow = tm + wm + i * 16 + row16;
        float inv = 1.f / rs[grow];
        float* dst = out + (long)bz * S * D + grow * D + tn + wn + cb;
#pragma unroll
        for (int q = 0; q < 4; q++) {
            float4 v = *(const float4*)&EP[row16 * 68 + cb + q * 4];
            v.x *= inv; v.y *= inv; v.z *= inv; v.w *= inv;
            *(float4*)(dst + q * 4) = v;
        }
    }
}

extern "C" void kernel_launch(void* const* d_in, const int* in_sizes, int n_in,
                              void* d_out, int out_size, void* d_ws, size_t ws_size,
                              hipStream_t stream) {
    const float* x    = (const float*)d_in[0];
    const float* mask = (const float*)d_in[1];
    const float* Wq   = (const float*)d_in[2];
    const float* bq   = (const float*)d_in[3];
    const float* Wk   = (const float*)d_in[4];
    const float* bk   = (const float*)d_in[5];
    const float* Wv   = (const float*)d_in[6];
    const float* bv   = (const float*)d_in[7];
    float* out = (float*)d_out;

    const int B = 4, S = 2048, D = 1024;
    const long MS = (long)B * S;  // 8192

    size_t need = (size_t)MS * D * 2 + (size_t)(2 * D) * D * 2 + (size_t)D * D * 2
                + (size_t)(2 * D) * 4 + (size_t)MS * (2 * D) * 2 + (size_t)D * MS * 2
                + (size_t)B * S * S * 2 + (size_t)B * S * 4 + (size_t)S * S * 2;
    if (ws_size < need) return;

    char* ws = (char*)d_ws;
    u16*  xb   = (u16*)ws;  ws += (long)MS * D * 2;
    u16*  wqkt = (u16*)ws;  ws += (long)(2 * D) * D * 2;
    u16*  wvt  = (u16*)ws;  ws += (long)D * D * 2;
    float* bqk = (float*)ws; ws += (long)(2 * D) * 4;
    u16*  QK   = (u16*)ws;  ws += (long)MS * (2 * D) * 2;
    u16*  VT   = (u16*)ws;  ws += (long)D * MS * 2;
    u16*  sc   = (u16*)ws;  ws += (long)B * S * S * 2;
    float* rsum = (float*)ws; ws += (long)B * S * 4;
    u16*  maskb = (u16*)ws; ws += (long)S * S * 2;

    const float SCALE = 0.03125f;  // 1/sqrt(1024)

    // 1) prep: x->bf16, W transposes, bias concat (11272 blocks)
    prep_kernel<<<11272, 256, 0, stream>>>(x, xb, Wq, Wk, Wv,
                                           wqkt, wqkt + (long)D * D, wvt, bq, bk, bqk);
    // 2) QK + VT GEMMs with mask-convert + rsum-zero folded into the grid tail
    gemm_qkvt_kernel<<<5664, 256, 0, stream>>>(xb, wqkt, wvt, QK, VT, bqk, bv,
                                               mask, maskb, rsum);
    // 3) scores (R4-proven gemm256, bf16 mask, softmax numerator fused)
    gemm256_kernel<<<dim3(S / 256, S / 256, B), 512, 0, stream>>>(
        QK, 2 * D, (long)S * 2 * D, QK + D, 2 * D, (long)S * 2 * D, sc, S, (long)S * S,
        maskb, S, rsum, S, SCALE, D);
    // 4) PV (R4-proven xcd map, softmax denominator fused)
    gemm_pv_kernel<<<dim3(8, 16, 4), 256, 0, stream>>>(sc, VT, out, rsum);
}